// Round 2
// baseline (335.625 us; speedup 1.0000x reference)
//
#include <hip/hip_runtime.h>

// Fused tensor-field + 3-layer MLP for MI355X (gfx950).
// 262144 pixels x 8 batches; per (pixel,batch) ~2080 f32 FMA => VALU-bound
// (no fp32-input MFMA on CDNA4; floor ~55us at 157.3 TF).
// Strategy: bilinear feature once per pixel (registers, reused across 8
// batches), z_feat per block (LDS broadcast), MLP weights via uniform scalar
// loads (s_load_dwordx16 + v_fmac with SGPR operand), 2 pixels/thread so each
// weight fetch feeds 64 FMAs. 512 blocks x 256 thr = 2 blocks/CU exactly at
// the 256-VGPR / 2-waves-per-SIMD occupancy from __launch_bounds__(256,2).
// Peak live VGPR ~210 (fa,fb live across batch loop + ha,hb,ga,gb) -> no spill.

constexpr int NPIX = 512 * 512;
constexpr int HALF = NPIX / 2;

__global__ __launch_bounds__(256, 2) void field_mlp_kernel(
    const float* __restrict__ z,        // [8]
    const float* __restrict__ data,     // [512,512,32]
    const float* __restrict__ z_data,   // [64,32]
    const float* __restrict__ lerp_w,   // [NPIX,2]
    const int* __restrict__ x0a, const int* __restrict__ y0a,
    const int* __restrict__ x1a, const int* __restrict__ y1a,
    const float* __restrict__ W1, const float* __restrict__ b1,
    const float* __restrict__ W2, const float* __restrict__ b2,
    const float* __restrict__ W3, const float* __restrict__ b3,
    float* __restrict__ out)            // [8,1,512,512]
{
    __shared__ float zf_lds[8][32];
    const int tid = threadIdx.x;

    // Cooperative z-feature: 256 threads cover 8 batches x 32 feats.
    {
        const int b = tid >> 5;
        const int i = tid & 31;
        const float zv = z[b];
        const float zn = 63.0f * zv;          // (Z_DIM-1)*(z-Z_MIN)/(Z_MAX-Z_MIN)
        int z0 = (int)zn;                     // trunc; zn >= 0
        z0 = max(0, min(z0, 63));
        const int z1 = min(z0 + 1, 63);
        const float zl = zn - truncf(zn);
        zf_lds[b][i] = z_data[z0 * 32 + i] * (1.0f - zl) + z_data[z1 * 32 + i] * zl;
    }
    __syncthreads();

    const int p0 = blockIdx.x * 256 + tid;
    const int p1 = p0 + HALF;

    float fa[32], fb[32];

    // Bilinear gather: 4 corners x 32 feats, 16B loads (cells are 128B-aligned).
    auto gather = [&](int p, float* f) {
        const int ix0 = x0a[p], iy0 = y0a[p], ix1 = x1a[p], iy1 = y1a[p];
        const float2 w2 = *(const float2*)(lerp_w + 2 * p);
        const float wx = w2.x, wy = w2.y;
        const float w00 = (1.0f - wx) * (1.0f - wy);
        const float w01 = wx * (1.0f - wy);
        const float w10 = (1.0f - wx) * wy;
        const float w11 = wx * wy;
        const float4* c00 = (const float4*)(data + (iy0 * 512 + ix0) * 32);
        const float4* c01 = (const float4*)(data + (iy0 * 512 + ix1) * 32);
        const float4* c10 = (const float4*)(data + (iy1 * 512 + ix0) * 32);
        const float4* c11 = (const float4*)(data + (iy1 * 512 + ix1) * 32);
#pragma unroll
        for (int q = 0; q < 8; ++q) {
            const float4 a = c00[q];
            const float4 b4 = c01[q];
            const float4 c = c10[q];
            const float4 d = c11[q];
            f[4 * q + 0] = a.x * w00 + b4.x * w01 + c.x * w10 + d.x * w11;
            f[4 * q + 1] = a.y * w00 + b4.y * w01 + c.y * w10 + d.y * w11;
            f[4 * q + 2] = a.z * w00 + b4.z * w01 + c.z * w10 + d.z * w11;
            f[4 * q + 3] = a.w * w00 + b4.w * w01 + c.w * w10 + d.w * w11;
        }
    };
    gather(p0, fa);
    gather(p1, fb);

    // Batch loop rolled (code size); layers fully unrolled so weight indices
    // are compile-time constants -> uniform s_load_dwordx16 fetches.
#pragma unroll 1
    for (int b = 0; b < 8; ++b) {
        float ha[32], hb[32];
#pragma unroll
        for (int j = 0; j < 32; ++j) {
            const float bv = b1[j];
            ha[j] = bv; hb[j] = bv;
        }
#pragma unroll
        for (int i = 0; i < 32; ++i) {
            const float zf = zf_lds[b][i];   // uniform broadcast, conflict-free
            const float va = fa[i] * zf;
            const float vb = fb[i] * zf;
#pragma unroll
            for (int j = 0; j < 32; ++j) {
                const float w = W1[i * 32 + j];
                ha[j] = fmaf(va, w, ha[j]);
                hb[j] = fmaf(vb, w, hb[j]);
            }
        }
#pragma unroll
        for (int j = 0; j < 32; ++j) {
            ha[j] = fmaxf(ha[j], 0.0f);
            hb[j] = fmaxf(hb[j], 0.0f);
        }

        float ga[32], gb[32];
#pragma unroll
        for (int j = 0; j < 32; ++j) {
            const float bv = b2[j];
            ga[j] = bv; gb[j] = bv;
        }
#pragma unroll
        for (int i = 0; i < 32; ++i) {
            const float va = ha[i];
            const float vb = hb[i];
#pragma unroll
            for (int j = 0; j < 32; ++j) {
                const float w = W2[i * 32 + j];
                ga[j] = fmaf(va, w, ga[j]);
                gb[j] = fmaf(vb, w, gb[j]);
            }
        }

        float oa = b3[0];
        float ob = b3[0];
#pragma unroll
        for (int i = 0; i < 32; ++i) {
            const float w = W3[i];
            oa = fmaf(fmaxf(ga[i], 0.0f), w, oa);
            ob = fmaf(fmaxf(gb[i], 0.0f), w, ob);
        }

        // Write-once 8 MB stream: nontemporal keeps it out of L2.
        __builtin_nontemporal_store(oa, out + b * NPIX + p0);
        __builtin_nontemporal_store(ob, out + b * NPIX + p1);
    }
}

extern "C" void kernel_launch(void* const* d_in, const int* in_sizes, int n_in,
                              void* d_out, int out_size, void* d_ws, size_t ws_size,
                              hipStream_t stream) {
    const float* zp      = (const float*)d_in[0];
    const float* data    = (const float*)d_in[1];
    const float* z_data  = (const float*)d_in[2];
    const float* lerp_w  = (const float*)d_in[3];
    const int*   x0      = (const int*)d_in[4];
    const int*   y0      = (const int*)d_in[5];
    const int*   x1      = (const int*)d_in[6];
    const int*   y1      = (const int*)d_in[7];
    const float* W1      = (const float*)d_in[8];
    const float* b1      = (const float*)d_in[9];
    const float* W2      = (const float*)d_in[10];
    const float* b2      = (const float*)d_in[11];
    const float* W3      = (const float*)d_in[12];
    const float* b3      = (const float*)d_in[13];
    float* out = (float*)d_out;

    dim3 grid(HALF / 256);   // 512 blocks
    dim3 block(256);
    hipLaunchKernelGGL(field_mlp_kernel, grid, block, 0, stream,
                       zp, data, z_data, lerp_w, x0, y0, x1, y1,
                       W1, b1, W2, b2, W3, b3, out);
}